// Round 1
// baseline (582.077 us; speedup 1.0000x reference)
//
#include <hip/hip_runtime.h>
#include <stdint.h>

// ---------------------------------------------------------------------------
// HolographicThoracicMemory on MI355X (gfx950)
// interference_weight[b,k] = s^T M_k s, M_k = (0.756/256) sum_c ref⊗obj
// All GEMMs via mfma_f32_16x16x32_bf16 (fp32 accumulate).
// R4: kill the barrier vmcnt(0) drains (T4 counted-vmcnt).
//  gemm1: raw s_barrier + vmcnt(1); X prefetch depth 2 (alternating regs,
//         2x-unrolled loop, XLOAD issued after STAGE_B so vmcnt order is
//         [.., gldsA, gldsB, xload] -> vmcnt(1) retires exactly the W pair).
//  cons:  28 x 64-K chunks, half-buffered Wh[2]; stage(p+1) issued right
//         after the single per-chunk __syncthreads, drained only at the next
//         one (full compute phase of overlap). Epilogue needs no barrier.
//  banks: stage k+1 after the post-MFMA lgkm-only barrier; interior barriers
//         are raw s_barrier+lgkmcnt(0) so the prefetch survives to the next
//         top-of-loop __syncthreads (overlaps reduce + epilogue).
// ---------------------------------------------------------------------------

typedef __attribute__((ext_vector_type(4))) float f32x4;
typedef __attribute__((ext_vector_type(8))) short s16x8;

#define SCALE_IW 0.002953125f  // 0.42 * 1.8 / 256

__device__ __forceinline__ ushort f2bf(float f) {
  uint32_t u = __builtin_bit_cast(uint32_t, f);
  u += 0x7fffu + ((u >> 16) & 1u);
  return (ushort)(u >> 16);
}
__device__ __forceinline__ float bf2f(ushort u) {
  return __builtin_bit_cast(float, ((uint32_t)u) << 16);
}
__device__ __forceinline__ void gl_lds16(const ushort* g, ushort* l) {
  __builtin_amdgcn_global_load_lds(
      (const __attribute__((address_space(1))) uint32_t*)g,
      (__attribute__((address_space(3))) uint32_t*)l, 16, 0, 0);
}
__device__ __forceinline__ f32x4 mfma16(s16x8 a, s16x8 b, f32x4 c) {
  return __builtin_amdgcn_mfma_f32_16x16x32_bf16(a, b, c, 0, 0, 0);
}

// raw barrier: producer-side lgkm drain before s_barrier; counted vmcnt keeps
// prefetch in flight. Trailing empty asm stops loads hoisting above s_barrier.
#define BARRIER_VM(N)                                                       \
  do {                                                                      \
    asm volatile("s_waitcnt vmcnt(" #N ") lgkmcnt(0)" ::: "memory");        \
    __builtin_amdgcn_s_barrier();                                           \
    asm volatile("" ::: "memory");                                          \
  } while (0)
#define BARRIER_LGKM()                                                      \
  do {                                                                      \
    asm volatile("s_waitcnt lgkmcnt(0)" ::: "memory");                      \
    __builtin_amdgcn_s_barrier();                                           \
    asm volatile("" ::: "memory");                                          \
  } while (0)

// ---------------------------------------------------------------------------
__global__ __launch_bounds__(256) void k_transpose(const float* __restrict__ src,
                                                   ushort* __restrict__ dst,
                                                   int R, int C) {
  __shared__ float tile[64][65];
  const int s = blockIdx.z;
  src += (size_t)s * R * C;
  dst += (size_t)s * R * C;
  const int c0 = blockIdx.x * 64, r0 = blockIdx.y * 64;
  const int tx = threadIdx.x, ty = threadIdx.y;
  for (int i = ty; i < 64; i += 4)
    tile[i][tx] = src[(size_t)(r0 + i) * C + (c0 + tx)];
  __syncthreads();
  for (int i = ty; i < 64; i += 4)
    dst[(size_t)(c0 + i) * R + (r0 + tx)] = f2bf(tile[tx][i]);
}

// ---------------------------------------------------------------------------
__global__ __launch_bounds__(128) void k_build_mt(const float* __restrict__ ref,
                                                  const float* __restrict__ obj,
                                                  ushort* __restrict__ mt) {
  const int k = blockIdx.y, e0 = blockIdx.x * 8, d = threadIdx.x;
  const float* rp = ref + (size_t)k * 256 * 128;
  const float* op = obj + (size_t)k * 256 * 128;
  float acc[8] = {};
  for (int c = 0; c < 256; ++c) {
    const float rv = rp[c * 128 + d];
#pragma unroll
    for (int j = 0; j < 8; ++j) acc[j] += rv * op[c * 128 + e0 + j];
  }
  ushort* o = mt + (size_t)k * 128 * 128;
#pragma unroll
  for (int j = 0; j < 8; ++j) o[(e0 + j) * 128 + d] = f2bf(acc[j] * SCALE_IW);
}

// ---------------------------------------------------------------------------
// GEMM1: X[B,3200](fp32, 3 segments) @ W1T[256n][3200k](bf16) -> relu -> H1 bf16
// grid (2 colhalves, 512 rowblocks), block 256. Tile 32 rows x 128 cols.
// K-step 32. Double-buffered As/Bs, ONE raw barrier/iter with vmcnt(1):
// W prefetch (issued last iter) must retire; this iter's W pair + the depth-2
// X load stay in flight. Tail iters drain with vmcnt(0).
// ---------------------------------------------------------------------------
__global__ __launch_bounds__(256, 4) void k_gemm1(
    const float* __restrict__ sup, const float* __restrict__ anom,
    const float* __restrict__ ind, const ushort* __restrict__ w1t,
    const float* __restrict__ b1, ushort* __restrict__ h1) {
  __shared__ alignas(16) ushort As[2][32 * 40];       // [row][k] pad->40
  __shared__ alignas(16) ushort Bs[2][4 * 128 * 8];   // [kc][n][8]
  const int t = threadIdx.x;
  const int w = t >> 6, l = t & 63, m = l & 15, q = l >> 4;
  const int n0 = blockIdx.x * 128;
  const int b0 = blockIdx.y * 32;
  const int ar = t >> 3, ac = t & 7;
  const ushort* wbase = w1t + (size_t)n0 * 3200;
  f32x4 acc[2][2] = {};
  float4 xq0, xq1;

#define XLOAD(KS, DST)                                                  \
  {                                                                     \
    const int k0_ = (KS) * 32;                                          \
    const float* src_;                                                  \
    int rs_, ko_;                                                       \
    if (k0_ < 1024)      { src_ = sup;  rs_ = 1024; ko_ = k0_; }        \
    else if (k0_ < 1152) { src_ = anom; rs_ = 128;  ko_ = k0_ - 1024; } \
    else                 { src_ = ind;  rs_ = 2048; ko_ = k0_ - 1152; } \
    DST = *(const float4*)(src_ + (size_t)(b0 + ar) * rs_ + ko_ + ac * 4); \
  }
#define STAGE_A(BUF, V)                                       \
  {                                                           \
    uint2 pk_;                                                \
    pk_.x = (uint)f2bf((V).x) | ((uint)f2bf((V).y) << 16);    \
    pk_.y = (uint)f2bf((V).z) | ((uint)f2bf((V).w) << 16);    \
    *(uint2*)(As[BUF] + ar * 40 + ac * 4) = pk_;              \
  }
#define STAGE_B(KS, BUF)                                                   \
  {                                                                        \
    const int k0_ = (KS) * 32;                                             \
    _Pragma("unroll")                                                      \
    for (int i_ = 0; i_ < 2; ++i_) {                                       \
      const int s_ = i_ * 256 + t, c_ = s_ >> 7, n_ = s_ & 127;            \
      gl_lds16(wbase + (size_t)n_ * 3200 + k0_ + c_ * 8,                   \
               Bs[BUF] + c_ * 1024 + n_ * 8);                              \
    }                                                                      \
  }
#define COMPUTE(CUR)                                                        \
  {                                                                         \
    s16x8 af_[2], bf_[2];                                                   \
    _Pragma("unroll")                                                       \
    for (int rt = 0; rt < 2; ++rt)                                          \
      af_[rt] = *(const s16x8*)(As[CUR] + (rt * 16 + m) * 40 + q * 8);      \
    _Pragma("unroll")                                                       \
    for (int ct = 0; ct < 2; ++ct)                                          \
      bf_[ct] = *(const s16x8*)(Bs[CUR] + q * 1024 + (w * 32 + ct * 16 + m) * 8); \
    _Pragma("unroll")                                                       \
    for (int rt = 0; rt < 2; ++rt)                                          \
      _Pragma("unroll")                                                     \
      for (int ct = 0; ct < 2; ++ct)                                        \
        acc[rt][ct] = mfma16(af_[rt], bf_[ct], acc[rt][ct]);                \
  }

  // Prologue: stage k-step 0; X for k-steps 1,2 into alternating regs.
  XLOAD(0, xq0);
  STAGE_A(0, xq0);
  STAGE_B(0, 0);
  asm volatile("" ::: "memory");  // keep XLOADs newer than the W pair
  XLOAD(1, xq0);
  XLOAD(2, xq1);

  // Steady state (2x unrolled so xq0/xq1 alternate with no register copy).
  // Per iter KS (cur=KS&1): stage buffers for KS+1, consume X(KS+1) from its
  // reg, refill same reg with X(KS+3). vmem issue order per iter:
  // [gldsA, gldsB, xload] -> barrier vmcnt(1) retires last iter's W pair and
  // any X >=2 intervals old; this iter's pair + fresh X stay in flight.
  for (int ks = 0; ks < 96; ks += 2) {
    BARRIER_VM(1);
    STAGE_B(ks + 1, 1);
    STAGE_A(1, xq0);
    asm volatile("" ::: "memory");
    XLOAD(ks + 3, xq0);
    COMPUTE(0);
    BARRIER_VM(1);
    STAGE_B(ks + 2, 0);
    STAGE_A(0, xq1);
    asm volatile("" ::: "memory");
    XLOAD(ks + 4, xq1);
    COMPUTE(1);
  }
  // Tail: ks = 96 (last XLOAD = 99), 97, 98 (staging only), 99 (compute only).
  BARRIER_VM(1);
  STAGE_B(97, 1);
  STAGE_A(1, xq0);
  asm volatile("" ::: "memory");
  XLOAD(99, xq0);
  COMPUTE(0);
  BARRIER_VM(1);
  STAGE_B(98, 0);
  STAGE_A(0, xq1);
  COMPUTE(1);
  BARRIER_VM(0);  // queue is [ga98,gb98]: must fully drain
  STAGE_B(99, 1);
  STAGE_A(1, xq0);
  COMPUTE(0);
  BARRIER_VM(0);
  COMPUTE(1);
#undef XLOAD
#undef STAGE_A
#undef STAGE_B
#undef COMPUTE
#pragma unroll
  for (int ct = 0; ct < 2; ++ct) {
    const int col = n0 + w * 32 + ct * 16 + m;
    const float bias = b1[col];
#pragma unroll
    for (int rt = 0; rt < 2; ++rt)
#pragma unroll
      for (int r = 0; r < 4; ++r) {
        const int row = b0 + rt * 16 + q * 4 + r;
        h1[(size_t)row * 256 + col] = f2bf(fmaxf(acc[rt][ct][r] + bias, 0.f));
      }
  }
}

// ---------------------------------------------------------------------------
// Consolidator: H1[B,256]->relu(@W2+b2)->12x relu(@Wl+bl)->state[B,128] bf16
// grid 512 (32 rows/block), block 256 = 4 waves; wave tile 32x32.
// R4: 28 x 64-K chunks (layer0 = chunks 0..3, layers 1..12 = 2 chunks each),
// Wh half-buffers 2x16KB. ONE __syncthreads per chunk: drains the stage of
// chunk p (issued a full compute phase ago) + makes prior LDS writes visible;
// stage(p+1) issued immediately after. Epilogue (dst != Asrc) needs no
// barrier; next chunk's sync covers visibility.
// ---------------------------------------------------------------------------
__global__ __launch_bounds__(256, 2) void k_cons(
    const ushort* __restrict__ h1, const ushort* __restrict__ w2t,
    const ushort* __restrict__ cwt, const float* __restrict__ b2,
    const float* __restrict__ cb, ushort* __restrict__ stateg) {
  __shared__ alignas(16) ushort A0[32 * 264];
  __shared__ alignas(16) ushort S0[32 * 136];
  __shared__ alignas(16) ushort S1[32 * 136];
  __shared__ alignas(16) ushort Wh[2][8 * 128 * 8];  // 2 x 16 KB half-buffers
  const int t = threadIdx.x;
  const int w = t >> 6, l = t & 63, m = l & 15, q = l >> 4;
  const int b0 = blockIdx.x * 32;

  auto stage = [&](int p) {
    const ushort* wsrc;
    int K, koff;
    if (p < 4) { wsrc = w2t; K = 256; koff = p * 64; }
    else {
      wsrc = cwt + (size_t)((p - 4) >> 1) * 16384;
      K = 128;
      koff = ((p - 4) & 1) * 64;
    }
    ushort* dst = Wh[p & 1];
#pragma unroll
    for (int i = 0; i < 4; ++i) {
      const int s = i * 256 + t, c = s >> 7, n = s & 127;
      gl_lds16(wsrc + (size_t)n * K + koff + c * 8, dst + c * 1024 + n * 8);
    }
  };

  stage(0);  // overlaps the A0 load below
#pragma unroll
  for (int i = 0; i < 4; ++i) {
    const int s = i * 256 + t, r = s >> 5, c = s & 31;
    *(uint4*)(A0 + r * 264 + c * 8) =
        *(const uint4*)(h1 + (size_t)(b0 + r) * 256 + c * 8);
  }

  f32x4 acc[2][2] = {};
  for (int p = 0; p < 28; ++p) {
    __syncthreads();  // drains stage(p) [vmcnt] + prior LDS writes [lgkm]
    if (p < 27) stage(p + 1);  // into Wh[(p+1)&1]; its last readers drained at
                               // the sync above (chunk p-1)
    const int layer = (p < 4) ? 0 : 1 + ((p - 4) >> 1);
    const ushort* Asrc;
    int astr, koff;
    if (p < 4) { Asrc = A0; astr = 264; koff = p * 64; }
    else {
      Asrc = (layer & 1) ? (const ushort*)S0 : (const ushort*)S1;
      astr = 136;
      koff = ((p - 4) & 1) * 64;
    }
    const ushort* Wb = Wh[p & 1];
#pragma unroll
    for (int ksl = 0; ksl < 2; ++ksl) {
      const int cl = ksl * 4 + q;  // local k-chunk slot in [0,8)
      s16x8 af[2];
#pragma unroll
      for (int rt = 0; rt < 2; ++rt)
        af[rt] = *(const s16x8*)(Asrc + (rt * 16 + m) * astr + koff + cl * 8);
#pragma unroll
      for (int ct = 0; ct < 2; ++ct) {
        const s16x8 bf =
            *(const s16x8*)(Wb + cl * 1024 + (w * 32 + ct * 16 + m) * 8);
#pragma unroll
        for (int rt = 0; rt < 2; ++rt)
          acc[rt][ct] = mfma16(af[rt], bf, acc[rt][ct]);
      }
    }
    const bool layer_end = (p == 3) || (p >= 4 && ((p - 4) & 1));
    if (layer_end) {
      const float* bias = (layer == 0) ? b2 : cb + (layer - 1) * 128;
      ushort* dst = (layer & 1) ? S1 : S0;
#pragma unroll
      for (int ct = 0; ct < 2; ++ct) {
        const int col = w * 32 + ct * 16 + m;
        const float bv = bias[col];
#pragma unroll
        for (int rt = 0; rt < 2; ++rt)
#pragma unroll
          for (int r = 0; r < 4; ++r) {
            dst[(rt * 16 + q * 4 + r) * 136 + col] =
                f2bf(fmaxf(acc[rt][ct][r] + bv, 0.f));
            acc[rt][ct][r] = 0.f;
          }
      }
    }
  }
  __syncthreads();
  const ushort* fin = S0;  // layer 12 (even) wrote S0
#pragma unroll
  for (int i = 0; i < 2; ++i) {
    const int s = i * 256 + t, r = s >> 4, c = s & 15;
    *(uint4*)(stateg + (size_t)(b0 + r) * 128 + c * 8) =
        *(const uint4*)(fin + r * 136 + c * 8);
  }
}

// ---------------------------------------------------------------------------
// Banks: per k: P=S@MT_k (iw = s^T M_k s), R=S@retWT_k;
//   out[b,k,e] = (iw + 0.3*mean|anom_b|) * (R[b,e] + ret_b[k,e])
// grid 512 (32 rows/block), block 256 = 4 waves; wave tile 32x32 per panel.
// R4: stage k+1 right after the post-MFMA lgkm barrier (all Mb/Rb reads
// drained there); interior barriers don't touch vmcnt, so the 32KB prefetch
// overlaps reduce + epilogue and drains at the next top __syncthreads.
// ---------------------------------------------------------------------------
__global__ __launch_bounds__(256, 2) void k_banks(
    const ushort* __restrict__ stateg, const float* __restrict__ anom,
    const ushort* __restrict__ mt, const ushort* __restrict__ rwt,
    const float* __restrict__ retb, float* __restrict__ out) {
  __shared__ alignas(16) ushort S[32 * 136];
  __shared__ alignas(16) ushort Mb[16 * 128 * 8];  // 32 KB
  __shared__ alignas(16) ushort Rb[16 * 128 * 8];  // 32 KB
  __shared__ alignas(16) float iwbuf[4][32];
  __shared__ alignas(16) float wvs[32];
  __shared__ alignas(16) float aws[32];
  const int t = threadIdx.x;
  const int w = t >> 6, l = t & 63, m = l & 15, q = l >> 4;
  const int b0 = blockIdx.x * 32;

  auto stagek = [&](int kk) {
#pragma unroll
    for (int i = 0; i < 8; ++i) {
      const int s = i * 256 + t, c = s >> 7, n = s & 127;
      gl_lds16(mt + (size_t)kk * 16384 + n * 128 + c * 8, Mb + c * 1024 + n * 8);
      gl_lds16(rwt + (size_t)kk * 16384 + n * 128 + c * 8, Rb + c * 1024 + n * 8);
    }
  };

  stagek(0);  // overlaps the whole prologue
#pragma unroll
  for (int i = 0; i < 2; ++i) {
    const int s = i * 256 + t, r = s >> 4, c = s & 15;
    *(uint4*)(S + r * 136 + c * 8) =
        *(const uint4*)(stateg + (size_t)(b0 + r) * 128 + c * 8);
  }
  {
    const int r = t >> 3, qq = t & 7;  // 8 threads/row, 16 floats each
    float sa = 0.f;
#pragma unroll
    for (int j = 0; j < 4; ++j) {
      const float4 v =
          *(const float4*)(anom + (size_t)(b0 + r) * 128 + qq * 16 + j * 4);
      sa += fabsf(v.x) + fabsf(v.y) + fabsf(v.z) + fabsf(v.w);
    }
    sa += __shfl_xor(sa, 1, 8);
    sa += __shfl_xor(sa, 2, 8);
    sa += __shfl_xor(sa, 4, 8);
    if (qq == 0) aws[r] = sa * (0.3f / 128.f);
  }
  __syncthreads();
  s16x8 af[4][2];  // [ks][rt] persistent state fragments
#pragma unroll
  for (int ks = 0; ks < 4; ++ks)
#pragma unroll
    for (int rt = 0; rt < 2; ++rt)
      af[ks][rt] = *(const s16x8*)(S + (rt * 16 + m) * 136 + (ks * 4 + q) * 8);
  float sc[2][4][2];  // [rt][reg][ct] fp32 state in C-layout lanes
#pragma unroll
  for (int rt = 0; rt < 2; ++rt)
#pragma unroll
    for (int r = 0; r < 4; ++r)
#pragma unroll
      for (int ct = 0; ct < 2; ++ct)
        sc[rt][r][ct] =
            bf2f(S[(rt * 16 + q * 4 + r) * 136 + (w * 32 + ct * 16 + m)]);

  for (int k = 0; k < 14; ++k) {
    __syncthreads();  // drains stage(k) [vmcnt(0)] + prior LDS writes
    f32x4 P[2][2] = {}, R[2][2] = {};
#pragma unroll
    for (int ks = 0; ks < 4; ++ks)
#pragma unroll
      for (int ct = 0; ct < 2; ++ct) {
        const int boff = (ks * 4 + q) * 1024 + (w * 32 + ct * 16 + m) * 8;
        const s16x8 bm = *(const s16x8*)(Mb + boff);
        const s16x8 br = *(const s16x8*)(Rb + boff);
#pragma unroll
        for (int rt = 0; rt < 2; ++rt) {
          P[rt][ct] = mfma16(af[ks][rt], bm, P[rt][ct]);
          R[rt][ct] = mfma16(af[ks][rt], br, R[rt][ct]);
        }
      }
#pragma unroll
    for (int rt = 0; rt < 2; ++rt) {
      float pr[4];
#pragma unroll
      for (int r = 0; r < 4; ++r) {
        float v = P[rt][0][r] * sc[rt][r][0] + P[rt][1][r] * sc[rt][r][1];
        v += __shfl_xor(v, 1, 16);
        v += __shfl_xor(v, 2, 16);
        v += __shfl_xor(v, 4, 16);
        v += __shfl_xor(v, 8, 16);
        pr[r] = v;
      }
      if (m == 0)
        *(float4*)&iwbuf[w][rt * 16 + q * 4] =
            make_float4(pr[0], pr[1], pr[2], pr[3]);
    }
    BARRIER_LGKM();  // iwbuf visible; all Mb/Rb ds_reads complete; NO vm drain
    if (k < 13) stagek(k + 1);  // overwrite Mb/Rb safely; overlaps the rest
    if (t < 32)
      wvs[t] = iwbuf[0][t] + iwbuf[1][t] + iwbuf[2][t] + iwbuf[3][t] + aws[t];
    BARRIER_LGKM();  // wvs visible; stage(k+1) still in flight
#pragma unroll
    for (int ct = 0; ct < 2; ++ct) {
      const int col = w * 32 + ct * 16 + m;
      const float rb = retb[k * 128 + col];
#pragma unroll
      for (int rt = 0; rt < 2; ++rt) {
        const float4 wv4 = *(const float4*)&wvs[rt * 16 + q * 4];
        const float wvv[4] = {wv4.x, wv4.y, wv4.z, wv4.w};
#pragma unroll
        for (int r = 0; r < 4; ++r) {
          const int row = b0 + rt * 16 + q * 4 + r;
          out[(size_t)row * 1792 + k * 128 + col] = wvv[r] * (R[rt][ct][r] + rb);
        }
      }
    }
  }
}

// ---------------------------------------------------------------------------
extern "C" void kernel_launch(void* const* d_in, const int* in_sizes, int n_in,
                              void* d_out, int out_size, void* d_ws,
                              size_t ws_size, hipStream_t stream) {
  const float* sup   = (const float*)d_in[0];
  const float* anom  = (const float*)d_in[1];
  const float* ind   = (const float*)d_in[2];
  const float* ipW1  = (const float*)d_in[3];
  const float* ipb1  = (const float*)d_in[4];
  const float* ipW2  = (const float*)d_in[5];
  const float* ipb2  = (const float*)d_in[6];
  const float* consW = (const float*)d_in[7];
  const float* consb = (const float*)d_in[8];
  const float* refp  = (const float*)d_in[9];
  const float* objp  = (const float*)d_in[10];
  const float* retW  = (const float*)d_in[11];
  const float* retb  = (const float*)d_in[12];
  float* out = (float*)d_out;
  char* ws = (char*)d_ws;
  ushort* W1T = (ushort*)(ws);             // 256 x 3200
  ushort* W2T = (ushort*)(ws + 1638400);   // 128 x 256
  ushort* CWT = (ushort*)(ws + 1703936);   // 12 x 128x128
  ushort* RWT = (ushort*)(ws + 2097152);   // 14 x 128x128
  ushort* MT  = (ushort*)(ws + 2555904);   // 14 x 128x128
  ushort* H1  = (ushort*)(ws + 3014656);   // 16384 x 256 bf16
  ushort* ST  = (ushort*)(ws + 11403264);  // 16384 x 128 bf16

  k_transpose<<<dim3(4, 50, 1), dim3(64, 4), 0, stream>>>(ipW1, W1T, 3200, 256);
  k_transpose<<<dim3(2, 4, 1), dim3(64, 4), 0, stream>>>(ipW2, W2T, 256, 128);
  k_transpose<<<dim3(2, 2, 12), dim3(64, 4), 0, stream>>>(consW, CWT, 128, 128);
  k_transpose<<<dim3(2, 2, 14), dim3(64, 4), 0, stream>>>(retW, RWT, 128, 128);
  k_build_mt<<<dim3(16, 14), 128, 0, stream>>>(refp, objp, MT);
  k_gemm1<<<dim3(2, 512), 256, 0, stream>>>(sup, anom, ind, W1T, ipb1, H1);
  k_cons<<<512, 256, 0, stream>>>(H1, W2T, CWT, ipb2, consb, ST);
  k_banks<<<512, 256, 0, stream>>>(ST, anom, MT, RWT, retb, out);
}

// Round 2
// 495.351 us; speedup vs baseline: 1.1751x; 1.1751x over previous
//
#include <hip/hip_runtime.h>
#include <stdint.h>

// ---------------------------------------------------------------------------
// HolographicThoracicMemory on MI355X (gfx950)
// interference_weight[b,k] = s^T M_k s, M_k = (0.756/256) sum_c ref⊗obj
// All GEMMs via mfma_f32_16x16x32_bf16 (fp32 accumulate).
// R5: contiguity + occupancy.
//  * ALL weights pre-swizzled into the exact LDS staging image, so every
//    gl_lds16 is (src + s*8 -> dst + s*8): 64 lanes x 16B contiguous = 1KB
//    dense per instruction (was 64 scattered lines at 25% utilization).
//  * gemm1: 16-row tiles, grid (2,1024) -> 8 blocks/CU (32 waves, was 16).
//    Reverted to the R3-proven structure: ONE __syncthreads/iter (full
//    drain), stage issued right after the barrier, drained one full compute
//    phase later; X register prefetch distance 2.
//  * cons/banks: R4 structures kept, staging now contiguous.
//  * k_transpose removed; k_prep_w1 / k_prep_nk build the swizzled layouts.
// ---------------------------------------------------------------------------

typedef __attribute__((ext_vector_type(4))) float f32x4;
typedef __attribute__((ext_vector_type(8))) short s16x8;

#define SCALE_IW 0.002953125f  // 0.42 * 1.8 / 256

__device__ __forceinline__ ushort f2bf(float f) {
  uint32_t u = __builtin_bit_cast(uint32_t, f);
  u += 0x7fffu + ((u >> 16) & 1u);
  return (ushort)(u >> 16);
}
__device__ __forceinline__ float bf2f(ushort u) {
  return __builtin_bit_cast(float, ((uint32_t)u) << 16);
}
__device__ __forceinline__ uint pack2(float a, float b) {
  return (uint)f2bf(a) | ((uint)f2bf(b) << 16);
}
__device__ __forceinline__ void gl_lds16(const ushort* g, ushort* l) {
  __builtin_amdgcn_global_load_lds(
      (const __attribute__((address_space(1))) uint32_t*)g,
      (__attribute__((address_space(3))) uint32_t*)l, 16, 0, 0);
}
__device__ __forceinline__ f32x4 mfma16(s16x8 a, s16x8 b, f32x4 c) {
  return __builtin_amdgcn_mfma_f32_16x16x32_bf16(a, b, c, 0, 0, 0);
}

#define BARRIER_LGKM()                                                      \
  do {                                                                      \
    asm volatile("s_waitcnt lgkmcnt(0)" ::: "memory");                      \
    __builtin_amdgcn_s_barrier();                                           \
    asm volatile("" ::: "memory");                                          \
  } while (0)

// ---------------------------------------------------------------------------
// W1 swizzle: W1S[(ch*100+ks)*4096 + c*1024 + n*8 + j] = bf16(ipW1[(ks*32+
// c*8+j)*256 + ch*128 + n]).  One block per (ks, ch); coalesced fp32 reads,
// contiguous 16B writes.
// ---------------------------------------------------------------------------
__global__ __launch_bounds__(256) void k_prep_w1(const float* __restrict__ w1,
                                                 ushort* __restrict__ w1s) {
  const int ks = blockIdx.x, ch = blockIdx.y, t = threadIdx.x;
  ushort* out = w1s + ((size_t)ch * 100 + ks) * 4096;
#pragma unroll
  for (int i = 0; i < 2; ++i) {
    const int p = i * 256 + t, c = p >> 7, n = p & 127;
    float v[8];
#pragma unroll
    for (int j = 0; j < 8; ++j)
      v[j] = w1[(size_t)(ks * 32 + c * 8 + j) * 256 + ch * 128 + n];
    uint4 o;
    o.x = pack2(v[0], v[1]);
    o.y = pack2(v[2], v[3]);
    o.z = pack2(v[4], v[5]);
    o.w = pack2(v[6], v[7]);
    *(uint4*)(out + (size_t)(c * 128 + n) * 8) = o;
  }
}

// ---------------------------------------------------------------------------
// Generic [K][128] fp32 -> swizzled bf16: out[(k>>3)*1024 + n*8 + (k&7)] =
// bf16(in[k*128 + n]). Block covers 16 k-rows (2 cg groups); slices via y.
// ---------------------------------------------------------------------------
__global__ __launch_bounds__(256) void k_prep_nk(const float* __restrict__ in,
                                                 ushort* __restrict__ out,
                                                 int in_slice, int out_slice) {
  const int t = threadIdx.x;
  const float* src = in + (size_t)blockIdx.y * in_slice;
  ushort* dst = out + (size_t)blockIdx.y * out_slice;
  const int cg = blockIdx.x * 2 + (t >> 7), n = t & 127;
  float v[8];
#pragma unroll
  for (int j = 0; j < 8; ++j) v[j] = src[(size_t)(cg * 8 + j) * 128 + n];
  uint4 o;
  o.x = pack2(v[0], v[1]);
  o.y = pack2(v[2], v[3]);
  o.z = pack2(v[4], v[5]);
  o.w = pack2(v[6], v[7]);
  *(uint4*)(dst + (size_t)cg * 1024 + n * 8) = o;
}

// ---------------------------------------------------------------------------
// M_k = scale * ref^T obj, written directly in the swizzled staging image:
// MS[k][(d>>3)*1024 + e*8 + (d&7)] = M'[e][d], M'[e][d] = sum_c r[c,d]o[c,e].
// ---------------------------------------------------------------------------
__global__ __launch_bounds__(128) void k_build_mt(const float* __restrict__ ref,
                                                  const float* __restrict__ obj,
                                                  ushort* __restrict__ ms) {
  const int k = blockIdx.y, e0 = blockIdx.x * 8, d = threadIdx.x;
  const float* rp = ref + (size_t)k * 256 * 128;
  const float* op = obj + (size_t)k * 256 * 128;
  float acc[8] = {};
  for (int c = 0; c < 256; ++c) {
    const float rv = rp[c * 128 + d];
#pragma unroll
    for (int j = 0; j < 8; ++j) acc[j] += rv * op[c * 128 + e0 + j];
  }
  ushort* o = ms + (size_t)k * 16384 + (d >> 3) * 1024 + (d & 7);
#pragma unroll
  for (int j = 0; j < 8; ++j) o[(e0 + j) * 8] = f2bf(acc[j] * SCALE_IW);
}

// ---------------------------------------------------------------------------
// GEMM1: X[B,3200](fp32) @ W1 -> relu -> H1[B,256] bf16.
// grid (2 colhalves, 1024 rowblocks) = 2048 blocks, 8/CU, 32 waves/CU.
// Tile 16 rows x 128 cols, K-step 32, dbuf, one __syncthreads/iter.
// Staging is fully contiguous from the pre-swizzled W1S.
// ---------------------------------------------------------------------------
__global__ __launch_bounds__(256, 8) void k_gemm1(
    const float* __restrict__ sup, const float* __restrict__ anom,
    const float* __restrict__ ind, const ushort* __restrict__ w1s,
    const float* __restrict__ b1, ushort* __restrict__ h1) {
  __shared__ alignas(16) ushort As[2][16 * 40];  // [row][k] pad->40
  __shared__ alignas(16) ushort Bs[2][4096];     // exact staging image, 8 KB
  const int t = threadIdx.x;
  const int w = t >> 6, l = t & 63, m = l & 15, q = l >> 4;
  const int n0 = blockIdx.x * 128;
  const int b0 = blockIdx.y * 16;
  const int ar = t >> 4, ac = t & 15;  // 16 threads/row, float2 each
  const ushort* wbase = w1s + (size_t)blockIdx.x * 409600;  // 100*4096
  f32x4 acc[2] = {};
  float2 xr;

#define XLOAD(KS)                                                         \
  {                                                                       \
    const int k0_ = (KS) * 32;                                            \
    const float* src_;                                                    \
    int rs_, ko_;                                                         \
    if (k0_ < 1024)      { src_ = sup;  rs_ = 1024; ko_ = k0_; }          \
    else if (k0_ < 1152) { src_ = anom; rs_ = 128;  ko_ = k0_ - 1024; }   \
    else                 { src_ = ind;  rs_ = 2048; ko_ = k0_ - 1152; }   \
    xr = *(const float2*)(src_ + (size_t)(b0 + ar) * rs_ + ko_ + ac * 2); \
  }
#define STAGE_A(BUF) \
  { *(uint*)(As[BUF] + ar * 40 + ac * 2) = pack2(xr.x, xr.y); }
#define STAGE_B(KS, BUF)                                       \
  {                                                            \
    _Pragma("unroll")                                          \
    for (int i_ = 0; i_ < 2; ++i_) {                           \
      const int s_ = i_ * 256 + t;                             \
      gl_lds16(wbase + (size_t)(KS) * 4096 + s_ * 8,           \
               Bs[BUF] + s_ * 8);                              \
    }                                                          \
  }

  XLOAD(0);
  STAGE_A(0);
  STAGE_B(0, 0);
  XLOAD(1);
  for (int ks = 0; ks < 100; ++ks) {
    __syncthreads();  // buf[ks&1] ready; prev reads done
    const int cur = ks & 1, nxt = cur ^ 1;
    if (ks < 99) {
      STAGE_A(nxt);             // consumes xr = X(ks+1)
      STAGE_B(ks + 1, nxt);
      if (ks < 98) XLOAD(ks + 2);
    }
    const s16x8 af = *(const s16x8*)(As[cur] + m * 40 + q * 8);
#pragma unroll
    for (int ct = 0; ct < 2; ++ct) {
      const s16x8 bf =
          *(const s16x8*)(Bs[cur] + q * 1024 + (w * 32 + ct * 16 + m) * 8);
      acc[ct] = mfma16(af, bf, acc[ct]);
    }
  }
#undef XLOAD
#undef STAGE_A
#undef STAGE_B
#pragma unroll
  for (int ct = 0; ct < 2; ++ct) {
    const int col = n0 + w * 32 + ct * 16 + m;
    const float bias = b1[col];
#pragma unroll
    for (int r = 0; r < 4; ++r) {
      const int row = b0 + q * 4 + r;
      h1[(size_t)row * 256 + col] = f2bf(fmaxf(acc[ct][r] + bias, 0.f));
    }
  }
}

// ---------------------------------------------------------------------------
// Consolidator: H1[B,256]->relu(@W2+b2)->12x relu(@Wl+bl)->state[B,128] bf16
// grid 512 (32 rows/block), block 256 = 4 waves; wave tile 32x32.
// 28 x 64-K chunks, half-buffered Wh[2]; ONE __syncthreads per chunk; stage
// of chunk p+1 issued right after it (drains a full compute phase later).
// Staging contiguous from pre-swizzled W2S/CWS.
// ---------------------------------------------------------------------------
__global__ __launch_bounds__(256, 2) void k_cons(
    const ushort* __restrict__ h1, const ushort* __restrict__ w2s,
    const ushort* __restrict__ cws, const float* __restrict__ b2,
    const float* __restrict__ cb, ushort* __restrict__ stateg) {
  __shared__ alignas(16) ushort A0[32 * 264];
  __shared__ alignas(16) ushort S0[32 * 136];
  __shared__ alignas(16) ushort S1[32 * 136];
  __shared__ alignas(16) ushort Wh[2][8192];  // 2 x 16 KB half-buffers
  const int t = threadIdx.x;
  const int w = t >> 6, l = t & 63, m = l & 15, q = l >> 4;
  const int b0 = blockIdx.x * 32;

  auto stage = [&](int p) {
    const ushort* src = (p < 4) ? w2s + (size_t)p * 8192
                                : cws + (size_t)(p - 4) * 8192;
    ushort* dst = Wh[p & 1];
#pragma unroll
    for (int i = 0; i < 4; ++i) {
      const int s = i * 256 + t;
      gl_lds16(src + s * 8, dst + s * 8);
    }
  };

  stage(0);  // overlaps the A0 load below
#pragma unroll
  for (int i = 0; i < 4; ++i) {
    const int s = i * 256 + t, r = s >> 5, c = s & 31;
    *(uint4*)(A0 + r * 264 + c * 8) =
        *(const uint4*)(h1 + (size_t)(b0 + r) * 256 + c * 8);
  }

  f32x4 acc[2][2] = {};
  for (int p = 0; p < 28; ++p) {
    __syncthreads();  // drains stage(p) [vmcnt] + prior LDS writes [lgkm]
    if (p < 27) stage(p + 1);
    const int layer = (p < 4) ? 0 : 1 + ((p - 4) >> 1);
    const ushort* Asrc;
    int astr, koff;
    if (p < 4) { Asrc = A0; astr = 264; koff = p * 64; }
    else {
      Asrc = (layer & 1) ? (const ushort*)S0 : (const ushort*)S1;
      astr = 136;
      koff = ((p - 4) & 1) * 64;
    }
    const ushort* Wb = Wh[p & 1];
#pragma unroll
    for (int ksl = 0; ksl < 2; ++ksl) {
      const int cl = ksl * 4 + q;
      s16x8 af[2];
#pragma unroll
      for (int rt = 0; rt < 2; ++rt)
        af[rt] = *(const s16x8*)(Asrc + (rt * 16 + m) * astr + koff + cl * 8);
#pragma unroll
      for (int ct = 0; ct < 2; ++ct) {
        const s16x8 bf =
            *(const s16x8*)(Wb + cl * 1024 + (w * 32 + ct * 16 + m) * 8);
#pragma unroll
        for (int rt = 0; rt < 2; ++rt)
          acc[rt][ct] = mfma16(af[rt], bf, acc[rt][ct]);
      }
    }
    const bool layer_end = (p == 3) || (p >= 4 && ((p - 4) & 1));
    if (layer_end) {
      const float* bias = (layer == 0) ? b2 : cb + (layer - 1) * 128;
      ushort* dst = (layer & 1) ? S1 : S0;
#pragma unroll
      for (int ct = 0; ct < 2; ++ct) {
        const int col = w * 32 + ct * 16 + m;
        const float bv = bias[col];
#pragma unroll
        for (int rt = 0; rt < 2; ++rt)
#pragma unroll
          for (int r = 0; r < 4; ++r) {
            dst[(rt * 16 + q * 4 + r) * 136 + col] =
                f2bf(fmaxf(acc[rt][ct][r] + bv, 0.f));
            acc[rt][ct][r] = 0.f;
          }
      }
    }
  }
  __syncthreads();
  const ushort* fin = S0;  // layer 12 (even) wrote S0
#pragma unroll
  for (int i = 0; i < 2; ++i) {
    const int s = i * 256 + t, r = s >> 4, c = s & 15;
    *(uint4*)(stateg + (size_t)(b0 + r) * 128 + c * 8) =
        *(const uint4*)(fin + r * 136 + c * 8);
  }
}

// ---------------------------------------------------------------------------
// Banks: per k: P=S@M_k (iw = s^T M_k s), R=S@retW_k;
//   out[b,k,e] = (iw + 0.3*mean|anom_b|) * (R[b,e] + ret_b[k,e])
// grid 512 (32 rows/block), 4 waves; stage k+1 right after the post-MFMA
// lgkm-only barrier (overlaps reduce + epilogue); contiguous from MS/RWS.
// ---------------------------------------------------------------------------
__global__ __launch_bounds__(256, 2) void k_banks(
    const ushort* __restrict__ stateg, const float* __restrict__ anom,
    const ushort* __restrict__ ms, const ushort* __restrict__ rws,
    const float* __restrict__ retb, float* __restrict__ out) {
  __shared__ alignas(16) ushort S[32 * 136];
  __shared__ alignas(16) ushort Mb[16384];  // 32 KB
  __shared__ alignas(16) ushort Rb[16384];  // 32 KB
  __shared__ alignas(16) float iwbuf[4][32];
  __shared__ alignas(16) float wvs[32];
  __shared__ alignas(16) float aws[32];
  const int t = threadIdx.x;
  const int w = t >> 6, l = t & 63, m = l & 15, q = l >> 4;
  const int b0 = blockIdx.x * 32;

  auto stagek = [&](int kk) {
#pragma unroll
    for (int i = 0; i < 8; ++i) {
      const int s = i * 256 + t;
      gl_lds16(ms + (size_t)kk * 16384 + s * 8, Mb + s * 8);
      gl_lds16(rws + (size_t)kk * 16384 + s * 8, Rb + s * 8);
    }
  };

  stagek(0);  // overlaps the whole prologue
#pragma unroll
  for (int i = 0; i < 2; ++i) {
    const int s = i * 256 + t, r = s >> 4, c = s & 15;
    *(uint4*)(S + r * 136 + c * 8) =
        *(const uint4*)(stateg + (size_t)(b0 + r) * 128 + c * 8);
  }
  {
    const int r = t >> 3, qq = t & 7;
    float sa = 0.f;
#pragma unroll
    for (int j = 0; j < 4; ++j) {
      const float4 v =
          *(const float4*)(anom + (size_t)(b0 + r) * 128 + qq * 16 + j * 4);
      sa += fabsf(v.x) + fabsf(v.y) + fabsf(v.z) + fabsf(v.w);
    }
    sa += __shfl_xor(sa, 1, 8);
    sa += __shfl_xor(sa, 2, 8);
    sa += __shfl_xor(sa, 4, 8);
    if (qq == 0) aws[r] = sa * (0.3f / 128.f);
  }
  __syncthreads();
  s16x8 af[4][2];
#pragma unroll
  for (int ks = 0; ks < 4; ++ks)
#pragma unroll
    for (int rt = 0; rt < 2; ++rt)
      af[ks][rt] = *(const s16x8*)(S + (rt * 16 + m) * 136 + (ks * 4 + q) * 8);
  float sc[2][4][2];
#pragma unroll
  for (int rt = 0; rt < 2; ++rt)
#pragma unroll
    for (int r = 0; r < 4; ++r)
#pragma unroll
      for (int ct = 0; ct < 2; ++ct)
        sc[rt][r][ct] =
            bf2f(S[(rt * 16 + q * 4 + r) * 136 + (w * 32 + ct * 16 + m)]);

  for (int k = 0; k < 14; ++k) {
    __syncthreads();  // drains stage(k) [vmcnt(0)] + prior LDS writes
    f32x4 P[2][2] = {}, R[2][2] = {};
#pragma unroll
    for (int ks = 0; ks < 4; ++ks)
#pragma unroll
      for (int ct = 0; ct < 2; ++ct) {
        const int boff = (ks * 4 + q) * 1024 + (w * 32 + ct * 16 + m) * 8;
        const s16x8 bm = *(const s16x8*)(Mb + boff);
        const s16x8 br = *(const s16x8*)(Rb + boff);
#pragma unroll
        for (int rt = 0; rt < 2; ++rt) {
          P[rt][ct] = mfma16(af[ks][rt], bm, P[rt][ct]);
          R[rt][ct] = mfma16(af[ks][rt], br, R[rt][ct]);
        }
      }
#pragma unroll
    for (int rt = 0; rt < 2; ++rt) {
      float pr[4];
#pragma unroll
      for (int r = 0; r < 4; ++r) {
        float v = P[rt][0][r] * sc[rt][r][0] + P[rt][1][r] * sc[rt][r][1];
        v += __shfl_xor(v, 1, 16);
        v += __shfl_xor(v, 2, 16);
        v += __shfl_xor(v, 4, 16);
        v += __shfl_xor(v, 8, 16);
        pr[r] = v;
      }
      if (m == 0)
        *(float4*)&iwbuf[w][rt * 16 + q * 4] =
            make_float4(pr[0], pr[1], pr[2], pr[3]);
    }
    BARRIER_LGKM();  // iwbuf visible; Mb/Rb ds_reads complete; NO vm drain
    if (k < 13) stagek(k + 1);  // overlaps reduce + epilogue
    if (t < 32)
      wvs[t] = iwbuf[0][t] + iwbuf[1][t] + iwbuf[2][t] + iwbuf[3][t] + aws[t];
    BARRIER_LGKM();  // wvs visible; stage(k+1) still in flight
#pragma unroll
    for (int ct = 0; ct < 2; ++ct) {
      const int col = w * 32 + ct * 16 + m;
      const float rb = retb[k * 128 + col];
#pragma unroll
      for (int rt = 0; rt < 2; ++rt) {
        const float4 wv4 = *(const float4*)&wvs[rt * 16 + q * 4];
        const float wvv[4] = {wv4.x, wv4.y, wv4.z, wv4.w};
#pragma unroll
        for (int r = 0; r < 4; ++r) {
          const int row = b0 + rt * 16 + q * 4 + r;
          out[(size_t)row * 1792 + k * 128 + col] = wvv[r] * (R[rt][ct][r] + rb);
        }
      }
    }
  }
}

// ---------------------------------------------------------------------------
extern "C" void kernel_launch(void* const* d_in, const int* in_sizes, int n_in,
                              void* d_out, int out_size, void* d_ws,
                              size_t ws_size, hipStream_t stream) {
  const float* sup   = (const float*)d_in[0];
  const float* anom  = (const float*)d_in[1];
  const float* ind   = (const float*)d_in[2];
  const float* ipW1  = (const float*)d_in[3];
  const float* ipb1  = (const float*)d_in[4];
  const float* ipW2  = (const float*)d_in[5];
  const float* ipb2  = (const float*)d_in[6];
  const float* consW = (const float*)d_in[7];
  const float* consb = (const float*)d_in[8];
  const float* refp  = (const float*)d_in[9];
  const float* objp  = (const float*)d_in[10];
  const float* retW  = (const float*)d_in[11];
  const float* retb  = (const float*)d_in[12];
  float* out = (float*)d_out;
  char* ws = (char*)d_ws;
  ushort* W1S = (ushort*)(ws);             // 2 x 100 x 4096 (swizzled)
  ushort* W2S = (ushort*)(ws + 1638400);   // 4 chunks x 8192
  ushort* CWS = (ushort*)(ws + 1703936);   // 12 x 16384
  ushort* RWS = (ushort*)(ws + 2097152);   // 14 x 16384
  ushort* MS  = (ushort*)(ws + 2555904);   // 14 x 16384
  ushort* H1  = (ushort*)(ws + 3014656);   // 16384 x 256 bf16
  ushort* ST  = (ushort*)(ws + 11403264);  // 16384 x 128 bf16

  k_prep_w1<<<dim3(100, 2), 256, 0, stream>>>(ipW1, W1S);
  k_prep_nk<<<dim3(16, 1), 256, 0, stream>>>(ipW2, W2S, 0, 0);
  k_prep_nk<<<dim3(8, 12), 256, 0, stream>>>(consW, CWS, 16384, 16384);
  k_prep_nk<<<dim3(8, 14), 256, 0, stream>>>(retW, RWS, 16384, 16384);
  k_build_mt<<<dim3(16, 14), 128, 0, stream>>>(refp, objp, MS);
  k_gemm1<<<dim3(2, 1024), 256, 0, stream>>>(sup, anom, ind, W1S, ipb1, H1);
  k_cons<<<512, 256, 0, stream>>>(H1, W2S, CWS, ipb2, consb, ST);
  k_banks<<<512, 256, 0, stream>>>(ST, anom, MS, RWS, retb, out);
}

// Round 3
// 434.222 us; speedup vs baseline: 1.3405x; 1.1408x over previous
//
#include <hip/hip_runtime.h>
#include <stdint.h>

// ---------------------------------------------------------------------------
// HolographicThoracicMemory on MI355X (gfx950)
// interference_weight[b,k] = s^T M_k s, M_k = (0.756/256) sum_c ref⊗obj
// All GEMMs via mfma_f32_16x16x32_bf16 (fp32 accumulate).
// R6: X-read DRAM-page locality. gemm1 back to R3 geometry (32-row tiles,
// grid (2,512), one __syncthreads/iter) + R5 contiguous W staging, and the
// X loads are issued as an 8-deep burst (8 consecutive float4 = 1KB/row
// clustered) every 8th iteration into a statically-indexed register ring.
// Theory: gemm1's 179us is the X HBM stream at ~1.2 TB/s because 128B/row
// at 12.8KB stride kills page locality; clustering restores it.
// ---------------------------------------------------------------------------

typedef __attribute__((ext_vector_type(4))) float f32x4;
typedef __attribute__((ext_vector_type(8))) short s16x8;

#define SCALE_IW 0.002953125f  // 0.42 * 1.8 / 256

__device__ __forceinline__ ushort f2bf(float f) {
  uint32_t u = __builtin_bit_cast(uint32_t, f);
  u += 0x7fffu + ((u >> 16) & 1u);
  return (ushort)(u >> 16);
}
__device__ __forceinline__ float bf2f(ushort u) {
  return __builtin_bit_cast(float, ((uint32_t)u) << 16);
}
__device__ __forceinline__ uint pack2(float a, float b) {
  return (uint)f2bf(a) | ((uint)f2bf(b) << 16);
}
__device__ __forceinline__ void gl_lds16(const ushort* g, ushort* l) {
  __builtin_amdgcn_global_load_lds(
      (const __attribute__((address_space(1))) uint32_t*)g,
      (__attribute__((address_space(3))) uint32_t*)l, 16, 0, 0);
}
__device__ __forceinline__ f32x4 mfma16(s16x8 a, s16x8 b, f32x4 c) {
  return __builtin_amdgcn_mfma_f32_16x16x32_bf16(a, b, c, 0, 0, 0);
}

#define BARRIER_LGKM()                                                      \
  do {                                                                      \
    asm volatile("s_waitcnt lgkmcnt(0)" ::: "memory");                      \
    __builtin_amdgcn_s_barrier();                                           \
    asm volatile("" ::: "memory");                                          \
  } while (0)

// ---------------------------------------------------------------------------
// W1 swizzle: W1S[(ch*100+ks)*4096 + c*1024 + n*8 + j] = bf16(ipW1[(ks*32+
// c*8+j)*256 + ch*128 + n]).  One block per (ks, ch); coalesced fp32 reads,
// contiguous 16B writes.
// ---------------------------------------------------------------------------
__global__ __launch_bounds__(256) void k_prep_w1(const float* __restrict__ w1,
                                                 ushort* __restrict__ w1s) {
  const int ks = blockIdx.x, ch = blockIdx.y, t = threadIdx.x;
  ushort* out = w1s + ((size_t)ch * 100 + ks) * 4096;
#pragma unroll
  for (int i = 0; i < 2; ++i) {
    const int p = i * 256 + t, c = p >> 7, n = p & 127;
    float v[8];
#pragma unroll
    for (int j = 0; j < 8; ++j)
      v[j] = w1[(size_t)(ks * 32 + c * 8 + j) * 256 + ch * 128 + n];
    uint4 o;
    o.x = pack2(v[0], v[1]);
    o.y = pack2(v[2], v[3]);
    o.z = pack2(v[4], v[5]);
    o.w = pack2(v[6], v[7]);
    *(uint4*)(out + (size_t)(c * 128 + n) * 8) = o;
  }
}

// ---------------------------------------------------------------------------
// Generic [K][128] fp32 -> swizzled bf16: out[(k>>3)*1024 + n*8 + (k&7)] =
// bf16(in[k*128 + n]). Block covers 16 k-rows (2 cg groups); slices via y.
// ---------------------------------------------------------------------------
__global__ __launch_bounds__(256) void k_prep_nk(const float* __restrict__ in,
                                                 ushort* __restrict__ out,
                                                 int in_slice, int out_slice) {
  const int t = threadIdx.x;
  const float* src = in + (size_t)blockIdx.y * in_slice;
  ushort* dst = out + (size_t)blockIdx.y * out_slice;
  const int cg = blockIdx.x * 2 + (t >> 7), n = t & 127;
  float v[8];
#pragma unroll
  for (int j = 0; j < 8; ++j) v[j] = src[(size_t)(cg * 8 + j) * 128 + n];
  uint4 o;
  o.x = pack2(v[0], v[1]);
  o.y = pack2(v[2], v[3]);
  o.z = pack2(v[4], v[5]);
  o.w = pack2(v[6], v[7]);
  *(uint4*)(dst + (size_t)cg * 1024 + n * 8) = o;
}

// ---------------------------------------------------------------------------
// M_k = scale * ref^T obj, written directly in the swizzled staging image:
// MS[k][(d>>3)*1024 + e*8 + (d&7)] = M'[e][d], M'[e][d] = sum_c r[c,d]o[c,e].
// ---------------------------------------------------------------------------
__global__ __launch_bounds__(128) void k_build_mt(const float* __restrict__ ref,
                                                  const float* __restrict__ obj,
                                                  ushort* __restrict__ ms) {
  const int k = blockIdx.y, e0 = blockIdx.x * 8, d = threadIdx.x;
  const float* rp = ref + (size_t)k * 256 * 128;
  const float* op = obj + (size_t)k * 256 * 128;
  float acc[8] = {};
  for (int c = 0; c < 256; ++c) {
    const float rv = rp[c * 128 + d];
#pragma unroll
    for (int j = 0; j < 8; ++j) acc[j] += rv * op[c * 128 + e0 + j];
  }
  ushort* o = ms + (size_t)k * 16384 + (d >> 3) * 1024 + (d & 7);
#pragma unroll
  for (int j = 0; j < 8; ++j) o[(e0 + j) * 8] = f2bf(acc[j] * SCALE_IW);
}

// ---------------------------------------------------------------------------
// GEMM1: X[B,3200](fp32) @ W1 -> relu -> H1[B,256] bf16.
// grid (2 colhalves, 512 rowblocks), block 256 = 4 waves. Tile 32x128,
// K-step 32, dbuf, one __syncthreads/iter. W staged contiguous from W1S.
// X loaded as 8-deep float4 bursts (1KB/row clustered) into a static ring.
// ---------------------------------------------------------------------------
__global__ __launch_bounds__(256, 4) void k_gemm1(
    const float* __restrict__ sup, const float* __restrict__ anom,
    const float* __restrict__ ind, const ushort* __restrict__ w1s,
    const float* __restrict__ b1, ushort* __restrict__ h1) {
  __shared__ alignas(16) ushort As[2][32 * 40];  // [row][k] pad->40
  __shared__ alignas(16) ushort Bs[2][4096];     // exact staging image, 8 KB
  const int t = threadIdx.x;
  const int w = t >> 6, l = t & 63, m = l & 15, q = l >> 4;
  const int n0 = blockIdx.x * 128;
  const int b0 = blockIdx.y * 32;
  const int ar = t >> 3, ac = t & 7;  // 8 threads/row, float4 each
  const ushort* wbase = w1s + (size_t)blockIdx.x * 409600;  // 100*4096
  f32x4 acc[2][2] = {};
  float4 xr[8];  // static-indexed register ring (rule #20: no runtime idx)

#define XLOAD(KS, SLOT)                                                   \
  {                                                                       \
    const int k0_ = (KS) * 32;                                            \
    const float* src_;                                                    \
    int rs_, ko_;                                                         \
    if (k0_ < 1024)      { src_ = sup;  rs_ = 1024; ko_ = k0_; }          \
    else if (k0_ < 1152) { src_ = anom; rs_ = 128;  ko_ = k0_ - 1024; }   \
    else                 { src_ = ind;  rs_ = 2048; ko_ = k0_ - 1152; }   \
    xr[SLOT] =                                                            \
        *(const float4*)(src_ + (size_t)(b0 + ar) * rs_ + ko_ + ac * 4);  \
  }
#define STAGE_A(BUF, SLOT)                                    \
  {                                                           \
    uint2 pk_;                                                \
    pk_.x = pack2(xr[SLOT].x, xr[SLOT].y);                    \
    pk_.y = pack2(xr[SLOT].z, xr[SLOT].w);                    \
    *(uint2*)(As[BUF] + ar * 40 + ac * 4) = pk_;              \
  }
#define STAGE_B(KS, BUF)                                       \
  {                                                            \
    _Pragma("unroll")                                          \
    for (int i_ = 0; i_ < 2; ++i_) {                           \
      const int s_ = i_ * 256 + t;                             \
      gl_lds16(wbase + (size_t)(KS) * 4096 + s_ * 8,           \
               Bs[BUF] + s_ * 8);                              \
    }                                                          \
  }
#define COMPUTE(CUR)                                                        \
  {                                                                         \
    s16x8 af_[2], bf_[2];                                                   \
    _Pragma("unroll")                                                       \
    for (int rt = 0; rt < 2; ++rt)                                          \
      af_[rt] = *(const s16x8*)(As[CUR] + (rt * 16 + m) * 40 + q * 8);      \
    _Pragma("unroll")                                                       \
    for (int ct = 0; ct < 2; ++ct)                                          \
      bf_[ct] =                                                             \
          *(const s16x8*)(Bs[CUR] + q * 1024 + (w * 32 + ct * 16 + m) * 8); \
    _Pragma("unroll")                                                       \
    for (int rt = 0; rt < 2; ++rt)                                          \
      _Pragma("unroll")                                                     \
      for (int ct = 0; ct < 2; ++ct)                                        \
        acc[rt][ct] = mfma16(af_[rt], bf_[ct], acc[rt][ct]);                \
  }

  // Prologue: X(0) staged directly; X(1) pre-loaded into slot 1.
  XLOAD(0, 0);
  STAGE_A(0, 0);
  STAGE_B(0, 0);
  XLOAD(1, 1);

  // Main: 12 groups of 8 (ks 0..95). At u==0 of each group, burst-load
  // X(g8+2..g8+9) into slots (2+j)&7 — 8 consecutive float4 = 1KB/row,
  // issued back-to-back for DRAM page locality. Slot (u+1)&7 is consumed
  // (STAGE_A) before the burst overwrites it (reg dependency orders it).
  for (int g = 0; g < 12; ++g) {
    const int g8 = g * 8;
#pragma unroll
    for (int u = 0; u < 8; ++u) {
      const int ks = g8 + u;
      __syncthreads();  // buf[ks&1] staged; prev reads done; X burst drained
      const int cur = u & 1, nxt = cur ^ 1;
      STAGE_A(nxt, (u + 1) & 7);
      STAGE_B(ks + 1, nxt);
      if (u == 0) {
#pragma unroll
        for (int j = 0; j < 8; ++j) XLOAD(g8 + 2 + j, (2 + j) & 7);
      }
      COMPUTE(cur);
    }
  }
  // Tail: ks = 96..99. X(96) in slot 0, X(97) slot 1 (from burst@88);
  // X(98)/X(99) loaded here into slots 2/3.
  __syncthreads();
  STAGE_A(1, 1);  // X(97)
  STAGE_B(97, 1);
  XLOAD(98, 2);
  XLOAD(99, 3);
  COMPUTE(0);
  __syncthreads();
  STAGE_A(0, 2);  // X(98)
  STAGE_B(98, 0);
  COMPUTE(1);
  __syncthreads();
  STAGE_A(1, 3);  // X(99)
  STAGE_B(99, 1);
  COMPUTE(0);
  __syncthreads();
  COMPUTE(1);
#undef XLOAD
#undef STAGE_A
#undef STAGE_B
#undef COMPUTE
#pragma unroll
  for (int ct = 0; ct < 2; ++ct) {
    const int col = n0 + w * 32 + ct * 16 + m;
    const float bias = b1[col];
#pragma unroll
    for (int rt = 0; rt < 2; ++rt)
#pragma unroll
      for (int r = 0; r < 4; ++r) {
        const int row = b0 + rt * 16 + q * 4 + r;
        h1[(size_t)row * 256 + col] = f2bf(fmaxf(acc[rt][ct][r] + bias, 0.f));
      }
  }
}

// ---------------------------------------------------------------------------
// Consolidator: H1[B,256]->relu(@W2+b2)->12x relu(@Wl+bl)->state[B,128] bf16
// grid 512 (32 rows/block), block 256 = 4 waves; wave tile 32x32.
// 28 x 64-K chunks, half-buffered Wh[2]; ONE __syncthreads per chunk; stage
// of chunk p+1 issued right after it (drains a full compute phase later).
// Staging contiguous from pre-swizzled W2S/CWS.
// ---------------------------------------------------------------------------
__global__ __launch_bounds__(256, 2) void k_cons(
    const ushort* __restrict__ h1, const ushort* __restrict__ w2s,
    const ushort* __restrict__ cws, const float* __restrict__ b2,
    const float* __restrict__ cb, ushort* __restrict__ stateg) {
  __shared__ alignas(16) ushort A0[32 * 264];
  __shared__ alignas(16) ushort S0[32 * 136];
  __shared__ alignas(16) ushort S1[32 * 136];
  __shared__ alignas(16) ushort Wh[2][8192];  // 2 x 16 KB half-buffers
  const int t = threadIdx.x;
  const int w = t >> 6, l = t & 63, m = l & 15, q = l >> 4;
  const int b0 = blockIdx.x * 32;

  auto stage = [&](int p) {
    const ushort* src = (p < 4) ? w2s + (size_t)p * 8192
                                : cws + (size_t)(p - 4) * 8192;
    ushort* dst = Wh[p & 1];
#pragma unroll
    for (int i = 0; i < 4; ++i) {
      const int s = i * 256 + t;
      gl_lds16(src + s * 8, dst + s * 8);
    }
  };

  stage(0);  // overlaps the A0 load below
#pragma unroll
  for (int i = 0; i < 4; ++i) {
    const int s = i * 256 + t, r = s >> 5, c = s & 31;
    *(uint4*)(A0 + r * 264 + c * 8) =
        *(const uint4*)(h1 + (size_t)(b0 + r) * 256 + c * 8);
  }

  f32x4 acc[2][2] = {};
  for (int p = 0; p < 28; ++p) {
    __syncthreads();  // drains stage(p) [vmcnt] + prior LDS writes [lgkm]
    if (p < 27) stage(p + 1);
    const int layer = (p < 4) ? 0 : 1 + ((p - 4) >> 1);
    const ushort* Asrc;
    int astr, koff;
    if (p < 4) { Asrc = A0; astr = 264; koff = p * 64; }
    else {
      Asrc = (layer & 1) ? (const ushort*)S0 : (const ushort*)S1;
      astr = 136;
      koff = ((p - 4) & 1) * 64;
    }
    const ushort* Wb = Wh[p & 1];
#pragma unroll
    for (int ksl = 0; ksl < 2; ++ksl) {
      const int cl = ksl * 4 + q;
      s16x8 af[2];
#pragma unroll
      for (int rt = 0; rt < 2; ++rt)
        af[rt] = *(const s16x8*)(Asrc + (rt * 16 + m) * astr + koff + cl * 8);
#pragma unroll
      for (int ct = 0; ct < 2; ++ct) {
        const s16x8 bf =
            *(const s16x8*)(Wb + cl * 1024 + (w * 32 + ct * 16 + m) * 8);
#pragma unroll
        for (int rt = 0; rt < 2; ++rt)
          acc[rt][ct] = mfma16(af[rt], bf, acc[rt][ct]);
      }
    }
    const bool layer_end = (p == 3) || (p >= 4 && ((p - 4) & 1));
    if (layer_end) {
      const float* bias = (layer == 0) ? b2 : cb + (layer - 1) * 128;
      ushort* dst = (layer & 1) ? S1 : S0;
#pragma unroll
      for (int ct = 0; ct < 2; ++ct) {
        const int col = w * 32 + ct * 16 + m;
        const float bv = bias[col];
#pragma unroll
        for (int rt = 0; rt < 2; ++rt)
#pragma unroll
          for (int r = 0; r < 4; ++r) {
            dst[(rt * 16 + q * 4 + r) * 136 + col] =
                f2bf(fmaxf(acc[rt][ct][r] + bv, 0.f));
            acc[rt][ct][r] = 0.f;
          }
      }
    }
  }
  __syncthreads();
  const ushort* fin = S0;  // layer 12 (even) wrote S0
#pragma unroll
  for (int i = 0; i < 2; ++i) {
    const int s = i * 256 + t, r = s >> 4, c = s & 15;
    *(uint4*)(stateg + (size_t)(b0 + r) * 128 + c * 8) =
        *(const uint4*)(fin + r * 136 + c * 8);
  }
}

// ---------------------------------------------------------------------------
// Banks: per k: P=S@M_k (iw = s^T M_k s), R=S@retW_k;
//   out[b,k,e] = (iw + 0.3*mean|anom_b|) * (R[b,e] + ret_b[k,e])
// grid 512 (32 rows/block), 4 waves; stage k+1 right after the post-MFMA
// lgkm-only barrier (overlaps reduce + epilogue); contiguous from MS/RWS.
// ---------------------------------------------------------------------------
__global__ __launch_bounds__(256, 2) void k_banks(
    const ushort* __restrict__ stateg, const float* __restrict__ anom,
    const ushort* __restrict__ ms, const ushort* __restrict__ rws,
    const float* __restrict__ retb, float* __restrict__ out) {
  __shared__ alignas(16) ushort S[32 * 136];
  __shared__ alignas(16) ushort Mb[16384];  // 32 KB
  __shared__ alignas(16) ushort Rb[16384];  // 32 KB
  __shared__ alignas(16) float iwbuf[4][32];
  __shared__ alignas(16) float wvs[32];
  __shared__ alignas(16) float aws[32];
  const int t = threadIdx.x;
  const int w = t >> 6, l = t & 63, m = l & 15, q = l >> 4;
  const int b0 = blockIdx.x * 32;

  auto stagek = [&](int kk) {
#pragma unroll
    for (int i = 0; i < 8; ++i) {
      const int s = i * 256 + t;
      gl_lds16(ms + (size_t)kk * 16384 + s * 8, Mb + s * 8);
      gl_lds16(rws + (size_t)kk * 16384 + s * 8, Rb + s * 8);
    }
  };

  stagek(0);  // overlaps the whole prologue
#pragma unroll
  for (int i = 0; i < 2; ++i) {
    const int s = i * 256 + t, r = s >> 4, c = s & 15;
    *(uint4*)(S + r * 136 + c * 8) =
        *(const uint4*)(stateg + (size_t)(b0 + r) * 128 + c * 8);
  }
  {
    const int r = t >> 3, qq = t & 7;
    float sa = 0.f;
#pragma unroll
    for (int j = 0; j < 4; ++j) {
      const float4 v =
          *(const float4*)(anom + (size_t)(b0 + r) * 128 + qq * 16 + j * 4);
      sa += fabsf(v.x) + fabsf(v.y) + fabsf(v.z) + fabsf(v.w);
    }
    sa += __shfl_xor(sa, 1, 8);
    sa += __shfl_xor(sa, 2, 8);
    sa += __shfl_xor(sa, 4, 8);
    if (qq == 0) aws[r] = sa * (0.3f / 128.f);
  }
  __syncthreads();
  s16x8 af[4][2];
#pragma unroll
  for (int ks = 0; ks < 4; ++ks)
#pragma unroll
    for (int rt = 0; rt < 2; ++rt)
      af[ks][rt] = *(const s16x8*)(S + (rt * 16 + m) * 136 + (ks * 4 + q) * 8);
  float sc[2][4][2];
#pragma unroll
  for (int rt = 0; rt < 2; ++rt)
#pragma unroll
    for (int r = 0; r < 4; ++r)
#pragma unroll
      for (int ct = 0; ct < 2; ++ct)
        sc[rt][r][ct] =
            bf2f(S[(rt * 16 + q * 4 + r) * 136 + (w * 32 + ct * 16 + m)]);

  for (int k = 0; k < 14; ++k) {
    __syncthreads();  // drains stage(k) [vmcnt(0)] + prior LDS writes
    f32x4 P[2][2] = {}, R[2][2] = {};
#pragma unroll
    for (int ks = 0; ks < 4; ++ks)
#pragma unroll
      for (int ct = 0; ct < 2; ++ct) {
        const int boff = (ks * 4 + q) * 1024 + (w * 32 + ct * 16 + m) * 8;
        const s16x8 bm = *(const s16x8*)(Mb + boff);
        const s16x8 br = *(const s16x8*)(Rb + boff);
#pragma unroll
        for (int rt = 0; rt < 2; ++rt) {
          P[rt][ct] = mfma16(af[ks][rt], bm, P[rt][ct]);
          R[rt][ct] = mfma16(af[ks][rt], br, R[rt][ct]);
        }
      }
#pragma unroll
    for (int rt = 0; rt < 2; ++rt) {
      float pr[4];
#pragma unroll
      for (int r = 0; r < 4; ++r) {
        float v = P[rt][0][r] * sc[rt][r][0] + P[rt][1][r] * sc[rt][r][1];
        v += __shfl_xor(v, 1, 16);
        v += __shfl_xor(v, 2, 16);
        v += __shfl_xor(v, 4, 16);
        v += __shfl_xor(v, 8, 16);
        pr[r] = v;
      }
      if (m == 0)
        *(float4*)&iwbuf[w][rt * 16 + q * 4] =
            make_float4(pr[0], pr[1], pr[2], pr[3]);
    }
    BARRIER_LGKM();  // iwbuf visible; Mb/Rb ds_reads complete; NO vm drain
    if (k < 13) stagek(k + 1);  // overlaps reduce + epilogue
    if (t < 32)
      wvs[t] = iwbuf[0][t] + iwbuf[1][t] + iwbuf[2][t] + iwbuf[3][t] + aws[t];
    BARRIER_LGKM();  // wvs visible; stage(k+1) still in flight
#pragma unroll
    for (int ct = 0; ct < 2; ++ct) {
      const int col = w * 32 + ct * 16 + m;
      const float rb = retb[k * 128 + col];
#pragma unroll
      for (int rt = 0; rt < 2; ++rt) {
        const float4 wv4 = *(const float4*)&wvs[rt * 16 + q * 4];
        const float wvv[4] = {wv4.x, wv4.y, wv4.z, wv4.w};
#pragma unroll
        for (int r = 0; r < 4; ++r) {
          const int row = b0 + rt * 16 + q * 4 + r;
          out[(size_t)row * 1792 + k * 128 + col] = wvv[r] * (R[rt][ct][r] + rb);
        }
      }
    }
  }
}

// ---------------------------------------------------------------------------
extern "C" void kernel_launch(void* const* d_in, const int* in_sizes, int n_in,
                              void* d_out, int out_size, void* d_ws,
                              size_t ws_size, hipStream_t stream) {
  const float* sup   = (const float*)d_in[0];
  const float* anom  = (const float*)d_in[1];
  const float* ind   = (const float*)d_in[2];
  const float* ipW1  = (const float*)d_in[3];
  const float* ipb1  = (const float*)d_in[4];
  const float* ipW2  = (const float*)d_in[5];
  const float* ipb2  = (const float*)d_in[6];
  const float* consW = (const float*)d_in[7];
  const float* consb = (const float*)d_in[8];
  const float* refp  = (const float*)d_in[9];
  const float* objp  = (const float*)d_in[10];
  const float* retW  = (const float*)d_in[11];
  const float* retb  = (const float*)d_in[12];
  float* out = (float*)d_out;
  char* ws = (char*)d_ws;
  ushort* W1S = (ushort*)(ws);             // 2 x 100 x 4096 (swizzled)
  ushort* W2S = (ushort*)(ws + 1638400);   // 4 chunks x 8192
  ushort* CWS = (ushort*)(ws + 1703936);   // 12 x 16384
  ushort* RWS = (ushort*)(ws + 2097152);   // 14 x 16384
  ushort* MS  = (ushort*)(ws + 2555904);   // 14 x 16384
  ushort* H1  = (ushort*)(ws + 3014656);   // 16384 x 256 bf16
  ushort* ST  = (ushort*)(ws + 11403264);  // 16384 x 128 bf16

  k_prep_w1<<<dim3(100, 2), 256, 0, stream>>>(ipW1, W1S);
  k_prep_nk<<<dim3(16, 1), 256, 0, stream>>>(ipW2, W2S, 0, 0);
  k_prep_nk<<<dim3(8, 12), 256, 0, stream>>>(consW, CWS, 16384, 16384);
  k_prep_nk<<<dim3(8, 14), 256, 0, stream>>>(retW, RWS, 16384, 16384);
  k_build_mt<<<dim3(16, 14), 128, 0, stream>>>(refp, objp, MS);
  k_gemm1<<<dim3(2, 512), 256, 0, stream>>>(sup, anom, ind, W1S, ipb1, H1);
  k_cons<<<512, 256, 0, stream>>>(H1, W2S, CWS, ipb2, consb, ST);
  k_banks<<<512, 256, 0, stream>>>(ST, anom, MS, RWS, retb, out);
}

// Round 4
// 421.616 us; speedup vs baseline: 1.3806x; 1.0299x over previous
//
#include <hip/hip_runtime.h>
#include <stdint.h>

// ---------------------------------------------------------------------------
// HolographicThoracicMemory on MI355X (gfx950)
// interference_weight[b,k] = s^T M_k s, M_k = (0.756/256) sum_c ref⊗obj
// All GEMMs via mfma_f32_16x16x32_bf16 (fp32 accumulate).
// R7: gemm1 deep pipeline (T3+T4): W staged distance-3 into Bs[4]; X in a
// 16-slot double-bank register ring, 8-burst issued one full 8-iter group
// ahead (min 7-iter slack); raw s_barrier with STATIC counted vmcnt
// (N[u] = {4,12,12,4,4,4,4,4}) so neither the X burst nor the in-flight W
// stages are ever drained in the main loop. Tail peeled to vmcnt(0).
// Also: 5 prep kernels merged into one (launches 8 -> 4).
// ---------------------------------------------------------------------------

typedef __attribute__((ext_vector_type(4))) float f32x4;
typedef __attribute__((ext_vector_type(8))) short s16x8;

#define SCALE_IW 0.002953125f  // 0.42 * 1.8 / 256

__device__ __forceinline__ ushort f2bf(float f) {
  uint32_t u = __builtin_bit_cast(uint32_t, f);
  u += 0x7fffu + ((u >> 16) & 1u);
  return (ushort)(u >> 16);
}
__device__ __forceinline__ float bf2f(ushort u) {
  return __builtin_bit_cast(float, ((uint32_t)u) << 16);
}
__device__ __forceinline__ uint pack2(float a, float b) {
  return (uint)f2bf(a) | ((uint)f2bf(b) << 16);
}
__device__ __forceinline__ void gl_lds16(const ushort* g, ushort* l) {
  __builtin_amdgcn_global_load_lds(
      (const __attribute__((address_space(1))) uint32_t*)g,
      (__attribute__((address_space(3))) uint32_t*)l, 16, 0, 0);
}
__device__ __forceinline__ f32x4 mfma16(s16x8 a, s16x8 b, f32x4 c) {
  return __builtin_amdgcn_mfma_f32_16x16x32_bf16(a, b, c, 0, 0, 0);
}

#define FENCE() asm volatile("" ::: "memory")
// raw barrier with counted vmcnt: in-flight prefetch survives the barrier.
#define BARRIER_VM(N)                                                       \
  do {                                                                      \
    asm volatile("s_waitcnt vmcnt(" #N ") lgkmcnt(0)" ::: "memory");        \
    __builtin_amdgcn_s_barrier();                                           \
    asm volatile("" ::: "memory");                                          \
  } while (0)
#define BARRIER_LGKM()                                                      \
  do {                                                                      \
    asm volatile("s_waitcnt lgkmcnt(0)" ::: "memory");                      \
    __builtin_amdgcn_s_barrier();                                           \
    asm volatile("" ::: "memory");                                          \
  } while (0)

// ---------------------------------------------------------------------------
// Merged prep: block ranges ->
//   [0,200)   W1 swizzle  (ks = b%100, ch = b/100)
//   [200,216) W2 swizzle
//   [216,312) consW swizzle (8 x 12)
//   [312,424) retW swizzle  (8 x 14)
//   [424,536) build M_k     (8 x 14, 256 thr: d = t&127, e0 half via t>>7)
// ---------------------------------------------------------------------------
__global__ __launch_bounds__(256) void k_prep(
    const float* __restrict__ w1, const float* __restrict__ w2,
    const float* __restrict__ cw, const float* __restrict__ rw,
    const float* __restrict__ ref, const float* __restrict__ obj,
    ushort* __restrict__ w1s, ushort* __restrict__ w2s,
    ushort* __restrict__ cws, ushort* __restrict__ rws,
    ushort* __restrict__ ms) {
  const int b = blockIdx.x, t = threadIdx.x;
  if (b < 200) {
    const int ks = b % 100, ch = b / 100;
    ushort* out = w1s + ((size_t)ch * 100 + ks) * 4096;
#pragma unroll
    for (int i = 0; i < 2; ++i) {
      const int p = i * 256 + t, c = p >> 7, n = p & 127;
      float v[8];
#pragma unroll
      for (int j = 0; j < 8; ++j)
        v[j] = w1[(size_t)(ks * 32 + c * 8 + j) * 256 + ch * 128 + n];
      uint4 o;
      o.x = pack2(v[0], v[1]);
      o.y = pack2(v[2], v[3]);
      o.z = pack2(v[4], v[5]);
      o.w = pack2(v[6], v[7]);
      *(uint4*)(out + (size_t)(c * 128 + n) * 8) = o;
    }
  } else if (b < 424) {
    const float* src;
    ushort* dst;
    int bx;
    if (b < 216) {
      src = w2; dst = w2s; bx = b - 200;
    } else if (b < 312) {
      const int bb = b - 216;
      src = cw + (size_t)(bb / 8) * 16384;
      dst = cws + (size_t)(bb / 8) * 16384;
      bx = bb % 8;
    } else {
      const int bb = b - 312;
      src = rw + (size_t)(bb / 8) * 16384;
      dst = rws + (size_t)(bb / 8) * 16384;
      bx = bb % 8;
    }
    const int cg = bx * 2 + (t >> 7), n = t & 127;
    float v[8];
#pragma unroll
    for (int j = 0; j < 8; ++j) v[j] = src[(size_t)(cg * 8 + j) * 128 + n];
    uint4 o;
    o.x = pack2(v[0], v[1]);
    o.y = pack2(v[2], v[3]);
    o.z = pack2(v[4], v[5]);
    o.w = pack2(v[6], v[7]);
    *(uint4*)(dst + (size_t)cg * 1024 + n * 8) = o;
  } else {
    const int bb = b - 424;
    const int k = bb / 8, e0 = (bb % 8) * 16 + (t >> 7) * 8, d = t & 127;
    const float* rp = ref + (size_t)k * 256 * 128;
    const float* op = obj + (size_t)k * 256 * 128;
    float acc[8] = {};
    for (int c = 0; c < 256; ++c) {
      const float rv = rp[c * 128 + d];
#pragma unroll
      for (int j = 0; j < 8; ++j) acc[j] += rv * op[c * 128 + e0 + j];
    }
    ushort* o = ms + (size_t)k * 16384 + (d >> 3) * 1024 + (d & 7);
#pragma unroll
    for (int j = 0; j < 8; ++j) o[(e0 + j) * 8] = f2bf(acc[j] * SCALE_IW);
  }
}

// ---------------------------------------------------------------------------
// GEMM1: X[B,3200](fp32) @ W1 -> relu -> H1[B,256] bf16.
// grid (2 colhalves, 512 rowblocks), block 256 = 4 waves. Tile 32x128,
// K-step 32. Deep pipeline: Bs[4] W ring staged at distance 3; xr[16] X
// ring (2 banks x 8), burst one group ahead; counted-vmcnt raw barriers.
// ---------------------------------------------------------------------------
__global__ __launch_bounds__(256, 4) void k_gemm1(
    const float* __restrict__ sup, const float* __restrict__ anom,
    const float* __restrict__ ind, const ushort* __restrict__ w1s,
    const float* __restrict__ b1, ushort* __restrict__ h1) {
  __shared__ alignas(16) ushort As[2][32 * 40];  // [row][k] pad->40, 2 bufs
  __shared__ alignas(16) ushort Bs[4][4096];     // 4-deep W ring, 32 KB
  const int t = threadIdx.x;
  const int w = t >> 6, l = t & 63, m = l & 15, q = l >> 4;
  const int n0 = blockIdx.x * 128;
  const int b0 = blockIdx.y * 32;
  const int ar = t >> 3, ac = t & 7;  // 8 threads/row, float4 each
  const ushort* wbase = w1s + (size_t)blockIdx.x * 409600;  // 100*4096
  f32x4 acc[2][2] = {};
  float4 xr[16];  // 2 banks x 8 slots, all statically indexed

#define XLOAD(KS, SLOT)                                                   \
  {                                                                       \
    const int kc_ = (KS) > 99 ? 99 : (KS);                                \
    const int k0_ = kc_ * 32;                                             \
    const float* src_;                                                    \
    int rs_, ko_;                                                         \
    if (k0_ < 1024)      { src_ = sup;  rs_ = 1024; ko_ = k0_; }          \
    else if (k0_ < 1152) { src_ = anom; rs_ = 128;  ko_ = k0_ - 1024; }   \
    else                 { src_ = ind;  rs_ = 2048; ko_ = k0_ - 1152; }   \
    xr[SLOT] =                                                            \
        *(const float4*)(src_ + (size_t)(b0 + ar) * rs_ + ko_ + ac * 4);  \
  }
#define STAGE_A(BUF, SLOT)                                    \
  {                                                           \
    uint2 pk_;                                                \
    pk_.x = pack2(xr[SLOT].x, xr[SLOT].y);                    \
    pk_.y = pack2(xr[SLOT].z, xr[SLOT].w);                    \
    *(uint2*)(As[BUF] + ar * 40 + ac * 4) = pk_;              \
  }
#define STAGE_B(KS, SLOT)                                      \
  {                                                            \
    _Pragma("unroll")                                          \
    for (int i_ = 0; i_ < 2; ++i_) {                           \
      const int s_ = i_ * 256 + t;                             \
      gl_lds16(wbase + (size_t)(KS) * 4096 + s_ * 8,           \
               Bs[SLOT] + s_ * 8);                             \
    }                                                          \
  }
#define BURST(G8, BK)                                          \
  {                                                            \
    _Pragma("unroll")                                          \
    for (int j_ = 0; j_ < 8; ++j_)                             \
      XLOAD((G8) + 8 + j_, j_ + 8 * ((BK) ^ 1));               \
  }
#define COMPUTE(AB, BSLOT)                                                  \
  {                                                                         \
    s16x8 af_[2], bf_[2];                                                   \
    _Pragma("unroll")                                                       \
    for (int rt = 0; rt < 2; ++rt)                                          \
      af_[rt] = *(const s16x8*)(As[AB] + (rt * 16 + m) * 40 + q * 8);       \
    _Pragma("unroll")                                                       \
    for (int ct = 0; ct < 2; ++ct)                                          \
      bf_[ct] =                                                             \
          *(const s16x8*)(Bs[BSLOT] + q * 1024 + (w * 32 + ct * 16 + m) * 8); \
    _Pragma("unroll")                                                       \
    for (int rt = 0; rt < 2; ++rt)                                          \
      _Pragma("unroll")                                                     \
      for (int ct = 0; ct < 2; ++ct)                                        \
        acc[rt][ct] = mfma16(af_[rt], bf_[ct], acc[rt][ct]);                \
  }
// One pipelined iteration. Issue order (pinned by FENCE):
//   barrier(vmcnt N) | STAGE_A (ds) | [u==0: BURST] | STAGE_B | COMPUTE
// N[u] = ops issued after stage(ks) (@iter ks-3): {4,12,12,4,4,4,4,4}.
#define ITER(G8, U, BK, NLIT, XSLOT)                           \
  {                                                            \
    BARRIER_VM(NLIT);                                          \
    STAGE_A(((U) + 1) & 1, XSLOT);                             \
    if ((U) == 0) { BURST(G8, BK); FENCE(); }                  \
    STAGE_B((G8) + (U) + 3, ((U) + 3) & 3);                    \
    FENCE();                                                   \
    COMPUTE((U) & 1, (U) & 3);                                 \
  }
#define GROUP(G8, BK)                                          \
  ITER(G8, 0, BK, 4,  (1 + 8 * (BK)))                          \
  ITER(G8, 1, BK, 12, (2 + 8 * (BK)))                          \
  ITER(G8, 2, BK, 12, (3 + 8 * (BK)))                          \
  ITER(G8, 3, BK, 4,  (4 + 8 * (BK)))                          \
  ITER(G8, 4, BK, 4,  (5 + 8 * (BK)))                          \
  ITER(G8, 5, BK, 4,  (6 + 8 * (BK)))                          \
  ITER(G8, 6, BK, 4,  (7 + 8 * (BK)))                          \
  ITER(G8, 7, BK, 4,  (8 * ((BK) ^ 1)))

  // Prologue: X(0..7) burst into bank 0; stage W k-steps 0..2; As[0] <- X(0).
#pragma unroll
  for (int j = 0; j < 8; ++j) XLOAD(j, j);
  FENCE();
  STAGE_B(0, 0);
  STAGE_B(1, 1);
  STAGE_B(2, 2);
  FENCE();
  STAGE_A(0, 0);

  // Groups 0..11 (ks 0..95), bank parity static via 2x group unroll.
  for (int gg = 0; gg < 6; ++gg) {
    const int h = gg * 16;
    GROUP(h, 0)
    GROUP(h + 8, 1)
  }
  // Tail ks = 96..99 (stage(99) at 96; drain to vmcnt(0)).
  BARRIER_VM(4);       // retire stage(96); in flight: g97,g98
  STAGE_A(1, 1);       // X(97)
  STAGE_B(99, 3);
  FENCE();
  COMPUTE(0, 0);       // ks=96
  BARRIER_VM(4);       // retire stage(97); in flight: g98,g99
  STAGE_A(0, 2);       // X(98)
  COMPUTE(1, 1);       // ks=97
  BARRIER_VM(2);       // retire stage(98); in flight: g99
  STAGE_A(1, 3);       // X(99)
  COMPUTE(0, 2);       // ks=98
  BARRIER_VM(0);
  COMPUTE(1, 3);       // ks=99
#undef XLOAD
#undef STAGE_A
#undef STAGE_B
#undef BURST
#undef COMPUTE
#undef ITER
#undef GROUP
#pragma unroll
  for (int ct = 0; ct < 2; ++ct) {
    const int col = n0 + w * 32 + ct * 16 + m;
    const float bias = b1[col];
#pragma unroll
    for (int rt = 0; rt < 2; ++rt)
#pragma unroll
      for (int r = 0; r < 4; ++r) {
        const int row = b0 + rt * 16 + q * 4 + r;
        h1[(size_t)row * 256 + col] = f2bf(fmaxf(acc[rt][ct][r] + bias, 0.f));
      }
  }
}

// ---------------------------------------------------------------------------
// Consolidator: H1[B,256]->relu(@W2+b2)->12x relu(@Wl+bl)->state[B,128] bf16
// grid 512 (32 rows/block), block 256 = 4 waves; wave tile 32x32.
// 28 x 64-K chunks, half-buffered Wh[2]; ONE __syncthreads per chunk; stage
// of chunk p+1 issued right after it (drains a full compute phase later).
// ---------------------------------------------------------------------------
__global__ __launch_bounds__(256, 2) void k_cons(
    const ushort* __restrict__ h1, const ushort* __restrict__ w2s,
    const ushort* __restrict__ cws, const float* __restrict__ b2,
    const float* __restrict__ cb, ushort* __restrict__ stateg) {
  __shared__ alignas(16) ushort A0[32 * 264];
  __shared__ alignas(16) ushort S0[32 * 136];
  __shared__ alignas(16) ushort S1[32 * 136];
  __shared__ alignas(16) ushort Wh[2][8192];  // 2 x 16 KB half-buffers
  const int t = threadIdx.x;
  const int w = t >> 6, l = t & 63, m = l & 15, q = l >> 4;
  const int b0 = blockIdx.x * 32;

  auto stage = [&](int p) {
    const ushort* src = (p < 4) ? w2s + (size_t)p * 8192
                                : cws + (size_t)(p - 4) * 8192;
    ushort* dst = Wh[p & 1];
#pragma unroll
    for (int i = 0; i < 4; ++i) {
      const int s = i * 256 + t;
      gl_lds16(src + s * 8, dst + s * 8);
    }
  };

  stage(0);  // overlaps the A0 load below
#pragma unroll
  for (int i = 0; i < 4; ++i) {
    const int s = i * 256 + t, r = s >> 5, c = s & 31;
    *(uint4*)(A0 + r * 264 + c * 8) =
        *(const uint4*)(h1 + (size_t)(b0 + r) * 256 + c * 8);
  }

  f32x4 acc[2][2] = {};
  for (int p = 0; p < 28; ++p) {
    __syncthreads();  // drains stage(p) [vmcnt] + prior LDS writes [lgkm]
    if (p < 27) stage(p + 1);
    const int layer = (p < 4) ? 0 : 1 + ((p - 4) >> 1);
    const ushort* Asrc;
    int astr, koff;
    if (p < 4) { Asrc = A0; astr = 264; koff = p * 64; }
    else {
      Asrc = (layer & 1) ? (const ushort*)S0 : (const ushort*)S1;
      astr = 136;
      koff = ((p - 4) & 1) * 64;
    }
    const ushort* Wb = Wh[p & 1];
#pragma unroll
    for (int ksl = 0; ksl < 2; ++ksl) {
      const int cl = ksl * 4 + q;
      s16x8 af[2];
#pragma unroll
      for (int rt = 0; rt < 2; ++rt)
        af[rt] = *(const s16x8*)(Asrc + (rt * 16 + m) * astr + koff + cl * 8);
#pragma unroll
      for (int ct = 0; ct < 2; ++ct) {
        const s16x8 bf =
            *(const s16x8*)(Wb + cl * 1024 + (w * 32 + ct * 16 + m) * 8);
#pragma unroll
        for (int rt = 0; rt < 2; ++rt)
          acc[rt][ct] = mfma16(af[rt], bf, acc[rt][ct]);
      }
    }
    const bool layer_end = (p == 3) || (p >= 4 && ((p - 4) & 1));
    if (layer_end) {
      const float* bias = (layer == 0) ? b2 : cb + (layer - 1) * 128;
      ushort* dst = (layer & 1) ? S1 : S0;
#pragma unroll
      for (int ct = 0; ct < 2; ++ct) {
        const int col = w * 32 + ct * 16 + m;
        const float bv = bias[col];
#pragma unroll
        for (int rt = 0; rt < 2; ++rt)
#pragma unroll
          for (int r = 0; r < 4; ++r) {
            dst[(rt * 16 + q * 4 + r) * 136 + col] =
                f2bf(fmaxf(acc[rt][ct][r] + bv, 0.f));
            acc[rt][ct][r] = 0.f;
          }
      }
    }
  }
  __syncthreads();
  const ushort* fin = S0;  // layer 12 (even) wrote S0
#pragma unroll
  for (int i = 0; i < 2; ++i) {
    const int s = i * 256 + t, r = s >> 4, c = s & 15;
    *(uint4*)(stateg + (size_t)(b0 + r) * 128 + c * 8) =
        *(const uint4*)(fin + r * 136 + c * 8);
  }
}

// ---------------------------------------------------------------------------
// Banks: per k: P=S@M_k (iw = s^T M_k s), R=S@retW_k;
//   out[b,k,e] = (iw + 0.3*mean|anom_b|) * (R[b,e] + ret_b[k,e])
// grid 512 (32 rows/block), 4 waves; stage k+1 right after the post-MFMA
// lgkm-only barrier (overlaps reduce + epilogue).
// ---------------------------------------------------------------------------
__global__ __launch_bounds__(256, 2) void k_banks(
    const ushort* __restrict__ stateg, const float* __restrict__ anom,
    const ushort* __restrict__ ms, const ushort* __restrict__ rws,
    const float* __restrict__ retb, float* __restrict__ out) {
  __shared__ alignas(16) ushort S[32 * 136];
  __shared__ alignas(16) ushort Mb[16384];  // 32 KB
  __shared__ alignas(16) ushort Rb[16384];  // 32 KB
  __shared__ alignas(16) float iwbuf[4][32];
  __shared__ alignas(16) float wvs[32];
  __shared__ alignas(16) float aws[32];
  const int t = threadIdx.x;
  const int w = t >> 6, l = t & 63, m = l & 15, q = l >> 4;
  const int b0 = blockIdx.x * 32;

  auto stagek = [&](int kk) {
#pragma unroll
    for (int i = 0; i < 8; ++i) {
      const int s = i * 256 + t;
      gl_lds16(ms + (size_t)kk * 16384 + s * 8, Mb + s * 8);
      gl_lds16(rws + (size_t)kk * 16384 + s * 8, Rb + s * 8);
    }
  };

  stagek(0);  // overlaps the whole prologue
#pragma unroll
  for (int i = 0; i < 2; ++i) {
    const int s = i * 256 + t, r = s >> 4, c = s & 15;
    *(uint4*)(S + r * 136 + c * 8) =
        *(const uint4*)(stateg + (size_t)(b0 + r) * 128 + c * 8);
  }
  {
    const int r = t >> 3, qq = t & 7;
    float sa = 0.f;
#pragma unroll
    for (int j = 0; j < 4; ++j) {
      const float4 v =
          *(const float4*)(anom + (size_t)(b0 + r) * 128 + qq * 16 + j * 4);
      sa += fabsf(v.x) + fabsf(v.y) + fabsf(v.z) + fabsf(v.w);
    }
    sa += __shfl_xor(sa, 1, 8);
    sa += __shfl_xor(sa, 2, 8);
    sa += __shfl_xor(sa, 4, 8);
    if (qq == 0) aws[r] = sa * (0.3f / 128.f);
  }
  __syncthreads();
  s16x8 af[4][2];
#pragma unroll
  for (int ks = 0; ks < 4; ++ks)
#pragma unroll
    for (int rt = 0; rt < 2; ++rt)
      af[ks][rt] = *(const s16x8*)(S + (rt * 16 + m) * 136 + (ks * 4 + q) * 8);
  float sc[2][4][2];
#pragma unroll
  for (int rt = 0; rt < 2; ++rt)
#pragma unroll
    for (int r = 0; r < 4; ++r)
#pragma unroll
      for (int ct = 0; ct < 2; ++ct)
        sc[rt][r][ct] =
            bf2f(S[(rt * 16 + q * 4 + r) * 136 + (w * 32 + ct * 16 + m)]);

  for (int k = 0; k < 14; ++k) {
    __syncthreads();  // drains stage(k) [vmcnt(0)] + prior LDS writes
    f32x4 P[2][2] = {}, R[2][2] = {};
#pragma unroll
    for (int ks = 0; ks < 4; ++ks)
#pragma unroll
      for (int ct = 0; ct < 2; ++ct) {
        const int boff = (ks * 4 + q) * 1024 + (w * 32 + ct * 16 + m) * 8;
        const s16x8 bm = *(const s16x8*)(Mb + boff);
        const s16x8 br = *(const s16x8*)(Rb + boff);
#pragma unroll
        for (int rt = 0; rt < 2; ++rt) {
          P[rt][ct] = mfma16(af[ks][rt], bm, P[rt][ct]);
          R[rt][ct] = mfma16(af[ks][rt], br, R[rt][ct]);
        }
      }
#pragma unroll
    for (int rt = 0; rt < 2; ++rt) {
      float pr[4];
#pragma unroll
      for (int r = 0; r < 4; ++r) {
        float v = P[rt][0][r] * sc[rt][r][0] + P[rt][1][r] * sc[rt][r][1];
        v += __shfl_xor(v, 1, 16);
        v += __shfl_xor(v, 2, 16);
        v += __shfl_xor(v, 4, 16);
        v += __shfl_xor(v, 8, 16);
        pr[r] = v;
      }
      if (m == 0)
        *(float4*)&iwbuf[w][rt * 16 + q * 4] =
            make_float4(pr[0], pr[1], pr[2], pr[3]);
    }
    BARRIER_LGKM();  // iwbuf visible; Mb/Rb ds_reads complete; NO vm drain
    if (k < 13) stagek(k + 1);  // overlaps reduce + epilogue
    if (t < 32)
      wvs[t] = iwbuf[0][t] + iwbuf[1][t] + iwbuf[2][t] + iwbuf[3][t] + aws[t];
    BARRIER_LGKM();  // wvs visible; stage(k+1) still in flight
#pragma unroll
    for (int ct = 0; ct < 2; ++ct) {
      const int col = w * 32 + ct * 16 + m;
      const float rb = retb[k * 128 + col];
#pragma unroll
      for (int rt = 0; rt < 2; ++rt) {
        const float4 wv4 = *(const float4*)&wvs[rt * 16 + q * 4];
        const float wvv[4] = {wv4.x, wv4.y, wv4.z, wv4.w};
#pragma unroll
        for (int r = 0; r < 4; ++r) {
          const int row = b0 + rt * 16 + q * 4 + r;
          out[(size_t)row * 1792 + k * 128 + col] = wvv[r] * (R[rt][ct][r] + rb);
        }
      }
    }
  }
}

// ---------------------------------------------------------------------------
extern "C" void kernel_launch(void* const* d_in, const int* in_sizes, int n_in,
                              void* d_out, int out_size, void* d_ws,
                              size_t ws_size, hipStream_t stream) {
  const float* sup   = (const float*)d_in[0];
  const float* anom  = (const float*)d_in[1];
  const float* ind   = (const float*)d_in[2];
  const float* ipW1  = (const float*)d_in[3];
  const float* ipb1  = (const float*)d_in[4];
  const float* ipW2  = (const float*)d_in[5];
  const float* ipb2  = (const float*)d_in[6];
  const float* consW = (const float*)d_in[7];
  const float* consb = (const float*)d_in[8];
  const float* refp  = (const float*)d_in[9];
  const float* objp  = (const float*)d_in[10];
  const float* retW  = (const float*)d_in[11];
  const float* retb  = (const float*)d_in[12];
  float* out = (float*)d_out;
  char* ws = (char*)d_ws;
  ushort* W1S = (ushort*)(ws);             // 2 x 100 x 4096 (swizzled)
  ushort* W2S = (ushort*)(ws + 1638400);   // 4 chunks x 8192
  ushort* CWS = (ushort*)(ws + 1703936);   // 12 x 16384
  ushort* RWS = (ushort*)(ws + 2097152);   // 14 x 16384
  ushort* MS  = (ushort*)(ws + 2555904);   // 14 x 16384
  ushort* H1  = (ushort*)(ws + 3014656);   // 16384 x 256 bf16
  ushort* ST  = (ushort*)(ws + 11403264);  // 16384 x 128 bf16

  k_prep<<<536, 256, 0, stream>>>(ipW1, ipW2, consW, retW, refp, objp,
                                  W1S, W2S, CWS, RWS, MS);
  k_gemm1<<<dim3(2, 512), 256, 0, stream>>>(sup, anom, ind, W1S, ipb1, H1);
  k_cons<<<512, 256, 0, stream>>>(H1, W2S, CWS, ipb2, consb, ST);
  k_banks<<<512, 256, 0, stream>>>(ST, anom, MS, RWS, retb, out);
}